// Round 6
// baseline (567.953 us; speedup 1.0000x reference)
//
#include <hip/hip_runtime.h>
#include <hip/hip_bf16.h>

#define H_DIM 2048
#define I_DIM 768
#define NEXP 64
#define TOPK 8
#define NTOK 1024   // B*S
#define BM 256      // token tile (count ~128+-11 => single chunk)
#define BKS 32      // K per step

typedef float f32x4 __attribute__((ext_vector_type(4)));
typedef float f32x2 __attribute__((ext_vector_type(2)));
typedef unsigned int u32x4 __attribute__((ext_vector_type(4)));
typedef unsigned int u32x2 __attribute__((ext_vector_type(2)));
typedef short bf16v8 __attribute__((ext_vector_type(8)));   // 8 bf16 in 4 VGPRs
typedef unsigned int u32;

// ---------------- workspace layout (bytes) ----------------
// topk_idx : int   [NTOK*TOPK]           @ 0
// topk_w   : float [NTOK*TOPK]           @ 32768
// counts   : int   [NEXP]                @ 65536
// offsets  : int   [NEXP]                @ 65792
// lists    : int   [NEXP*NTOK]           @ 66048
// wlist    : float [NEXP*NTOK]           @ 328192
// hmid     : bf16  [NTOK*TOPK * I_DIM]   @ 590336   (12.58 MB)
// xbf      : bf16  [NTOK * H_DIM]        @ 13173248 (4 MB)

__device__ inline unsigned short f2bf(float f) {
    union { float f; u32 u; } v; v.f = f;
    u32 r = (v.u + 0x7FFFu + ((v.u >> 16) & 1u)) >> 16;
    return (unsigned short)r;
}
__device__ inline u32 pack2(float a, float b) {
    return (u32)f2bf(a) | ((u32)f2bf(b) << 16);
}

__global__ void zero_kernel(float4* p, int n4) {
    int i = blockIdx.x * blockDim.x + threadIdx.x;
    if (i < n4) p[i] = (float4){0.f, 0.f, 0.f, 0.f};
}

// fp32 x -> bf16 copy
__global__ void xconv_kernel(const float4* __restrict__ x, ushort4* __restrict__ xbf, int n4) {
    int i = blockIdx.x * blockDim.x + threadIdx.x;
    if (i < n4) {
        float4 v = x[i];
        ushort4 o;
        o.x = f2bf(v.x); o.y = f2bf(v.y); o.z = f2bf(v.z); o.w = f2bf(v.w);
        xbf[i] = o;
    }
}

// one block per token, 64 threads (one per expert) -- verified R1-R5
__global__ __launch_bounds__(64) void router_kernel(
    const float* __restrict__ x, const float* __restrict__ Wr,
    int* __restrict__ topk_idx, float* __restrict__ topk_w)
{
    const int t = blockIdx.x;
    const int e = threadIdx.x;
    __shared__ float xs[H_DIM];

    const float* xrow = x + (size_t)t * H_DIM;
    #pragma unroll
    for (int m = 0; m < H_DIM / 64; ++m) xs[m * 64 + e] = xrow[m * 64 + e];
    __syncthreads();

    float acc = 0.f;
    #pragma unroll 8
    for (int h = 0; h < H_DIM; ++h) acc += xs[h] * Wr[(size_t)h * NEXP + e];

    float m = acc;
    #pragma unroll
    for (int o = 32; o > 0; o >>= 1) m = fmaxf(m, __shfl_xor(m, o));
    float p = __expf(acc - m);
    float s = p;
    #pragma unroll
    for (int o = 32; o > 0; o >>= 1) s += __shfl_xor(s, o);
    float prob = p / s;

    float myp = prob;
    float kw[TOPK]; int kid[TOPK]; float wsum = 0.f;
    #pragma unroll
    for (int k = 0; k < TOPK; ++k) {
        float v = myp; int bi = e;
        #pragma unroll
        for (int o = 32; o > 0; o >>= 1) {
            float ov = __shfl_xor(v, o);
            int   oi = __shfl_xor(bi, o);
            if (ov > v || (ov == v && oi < bi)) { v = ov; bi = oi; }
        }
        kw[k] = v; kid[k] = bi; wsum += v;
        if (e == bi) myp = -1.f;
    }
    if (e == 0) {
        float inv = 1.f / wsum;
        #pragma unroll
        for (int k = 0; k < TOPK; ++k) {
            topk_idx[t * TOPK + k] = kid[k];
            topk_w[t * TOPK + k]   = kw[k] * inv;
        }
    }
}

__global__ __launch_bounds__(64) void listbuild_kernel(
    const int* __restrict__ topk_idx, const float* __restrict__ topk_w,
    int* __restrict__ counts, int* __restrict__ lists, float* __restrict__ wlist)
{
    const int e = blockIdx.x;
    const int lane = threadIdx.x;
    int n = 0;
    for (int base = 0; base < NTOK * TOPK; base += 64) {
        int s = base + lane;
        int idx = topk_idx[s];
        bool match = (idx == e);
        unsigned long long mask = __ballot(match);
        int pre = __popcll(mask & ((1ull << lane) - 1ull));
        if (match) {
            lists[e * NTOK + n + pre] = s >> 3;
            wlist[e * NTOK + n + pre] = topk_w[s];
        }
        n += __popcll(mask);
    }
    if (lane == 0) counts[e] = n;
}

__global__ __launch_bounds__(64) void scan_kernel(
    const int* __restrict__ counts, int* __restrict__ offsets)
{
    int e = threadIdx.x;
    int v = counts[e];
    int xacc = v;
    #pragma unroll
    for (int o = 1; o < 64; o <<= 1) {
        int y = __shfl_up(xacc, o);
        if (e >= o) xacc += y;
    }
    offsets[e] = xacc - v;
}

// ---------------- MFMA gate+up: grid 1536 (xcd-swizzled), block 512, BN=32 ----------------
__global__ __launch_bounds__(512) void gateup_kernel(
    const unsigned short* __restrict__ xbf,
    const float* __restrict__ Wg, const float* __restrict__ Wu,
    const int* __restrict__ counts, const int* __restrict__ offsets,
    const int* __restrict__ lists, const float* __restrict__ wlist,
    unsigned short* __restrict__ hmid)
{
    // bijective XCD swizzle: 1536 = 8 * 192; same-expert blocks stay on one XCD
    const int b  = blockIdx.x;
    const int wg = (b & 7) * 192 + (b >> 3);
    const int itile = wg % 24;                // 24 itiles of 32 cols
    const int e     = wg / 24;

    const int count = counts[e];
    if (count == 0) return;
    const int off = offsets[e];
    const int i0 = itile * 32;

    __shared__ unsigned short Alds[BM][40];   // 20480 B
    __shared__ u32 Bgl[32 * 20];              // 2560 B  [n][kpair swizzled]
    __shared__ u32 Bul[32 * 20];              // 2560 B

    const int tid  = threadIdx.x;
    const int lane = tid & 63;
    const int wid  = tid >> 6;
    const int wm   = wid >> 1, wn = wid & 1;  // wave grid 4(M) x 2(N); wave tile 64x16
    const int kb   = lane >> 4;
    const int l15  = lane & 15;

    const float* WgE = Wg + (size_t)e * H_DIM * I_DIM + i0;
    const float* WuE = Wu + (size_t)e * H_DIM * I_DIM + i0;

    // A stage: thread -> (row, 16-short half)
    const int ar = tid >> 1;
    const int ah = (tid & 1) * 16;
    // B stage: thread -> (col bnn, 4 k-rows starting 4*bkq, matrix bmat)
    const int bnn  = tid & 31;
    const int bkq  = (tid >> 5) & 7;
    const int bmat = tid >> 8;                // 0 = gate, 1 = up
    const float* WB = bmat ? WuE : WgE;
    // swizzled b64 destination: word = bnn*20 + ((2*bkq) ^ key4)
    const int key4w = 4 * ((bnn >> 3) & 3);
    u32* bdst = (bmat ? Bul : Bgl) + bnn * 20 + ((2 * bkq) ^ key4w);
    // B fragment read offset (per lane): n = wn*16 + l15
    const int brn   = wn * 16 + l15;
    const int key4r = 4 * ((brn >> 3) & 3);

    for (int mstart = 0; mstart < count; mstart += BM) {
        const int pr = mstart + ar;
        const bool aact = pr < count;
        const unsigned short* xrow = xbf + (size_t)(aact ? lists[e * NTOK + pr] : 0) * H_DIM + ah;
        const bool mact = (mstart + wm * 64) < count;

        f32x4 accg[4], accu[4];
        #pragma unroll
        for (int i = 0; i < 4; ++i) {
            accg[i] = (f32x4){0.f, 0.f, 0.f, 0.f};
            accu[i] = (f32x4){0.f, 0.f, 0.f, 0.f};
        }

        u32x4 pA0, pA1;                       // A prefetch (1-deep)
        float b0a, b1a, b2a, b3a;             // B prefetch set 0
        float b0b, b1b, b2b, b3b;             // B prefetch set 1

#define LOADA(h)                                                                \
        if (aact) {                                                             \
            const u32x4* pa_ = (const u32x4*)(xrow + (h));                      \
            pA0 = pa_[0]; pA1 = pa_[1];                                         \
        }
#define LOADB(R0,R1,R2,R3,h)                                                    \
        {                                                                       \
            R0 = __builtin_nontemporal_load(WB + (size_t)((h) + 4 * bkq)     * I_DIM + bnn); \
            R1 = __builtin_nontemporal_load(WB + (size_t)((h) + 4 * bkq + 1) * I_DIM + bnn); \
            R2 = __builtin_nontemporal_load(WB + (size_t)((h) + 4 * bkq + 2) * I_DIM + bnn); \
            R3 = __builtin_nontemporal_load(WB + (size_t)((h) + 4 * bkq + 3) * I_DIM + bnn); \
        }
#define STOREA()                                                                \
        if (aact) {                                                             \
            *(u32x4*)&Alds[ar][ah]     = pA0;                                   \
            *(u32x4*)&Alds[ar][ah + 8] = pA1;                                   \
        }
#define STOREB(R0,R1,R2,R3)                                                     \
        {                                                                       \
            u32x2 w_; w_.x = pack2(R0, R1); w_.y = pack2(R2, R3);               \
            *(u32x2*)bdst = w_;                                                 \
        }
#define MFMA_PHASE()                                                            \
        if (mact) {                                                             \
            bf16v8 af[4], bg, bu;                                               \
            _Pragma("unroll")                                                   \
            for (int mf = 0; mf < 4; ++mf)                                      \
                af[mf] = *(const bf16v8*)&Alds[wm * 64 + mf * 16 + l15][kb * 8];\
            bg = *(const bf16v8*)&Bgl[brn * 20 + ((4 * kb) ^ key4r)];           \
            bu = *(const bf16v8*)&Bul[brn * 20 + ((4 * kb) ^ key4r)];           \
            _Pragma("unroll")                                                   \
            for (int mf = 0; mf < 4; ++mf) {                                    \
                accg[mf] = __builtin_amdgcn_mfma_f32_16x16x32_bf16(af[mf], bg, accg[mf], 0, 0, 0); \
                accu[mf] = __builtin_amdgcn_mfma_f32_16x16x32_bf16(af[mf], bu, accu[mf], 0, 0, 0); \
            }                                                                   \
        }

        LOADB(b0a, b1a, b2a, b3a, 0);
        LOADB(b0b, b1b, b2b, b3b, BKS);
        LOADA(0);

        for (int hh = 0; hh < H_DIM; hh += 2 * BKS) {
            STOREA(); STOREB(b0a, b1a, b2a, b3a);
            __syncthreads();
            if (hh + 2 * BKS < H_DIM) LOADB(b0a, b1a, b2a, b3a, hh + 2 * BKS);
            LOADA(hh + BKS);
            MFMA_PHASE();
            __syncthreads();

            STOREA(); STOREB(b0b, b1b, b2b, b3b);
            __syncthreads();
            if (hh + 3 * BKS < H_DIM) LOADB(b0b, b1b, b2b, b3b, hh + 3 * BKS);
            if (hh + 2 * BKS < H_DIM) LOADA(hh + 2 * BKS);
            MFMA_PHASE();
            __syncthreads();
        }
#undef LOADA
#undef LOADB
#undef STOREA
#undef STOREB
#undef MFMA_PHASE

        // ---- epilogue: silu(g)*u*w -> hmid (bf16) ----
        if (mact) {
            #pragma unroll
            for (int mf = 0; mf < 4; ++mf)
                #pragma unroll
                for (int r = 0; r < 4; ++r) {
                    int pos = mstart + wm * 64 + mf * 16 + kb * 4 + r;
                    if (pos < count) {
                        float wgt = wlist[e * NTOK + pos];
                        float g = accg[mf][r], u = accu[mf][r];
                        float s = 1.f / (1.f + __expf(-g));
                        float h = g * s * u * wgt;
                        hmid[(size_t)(off + pos) * I_DIM + i0 + wn * 16 + l15] = f2bf(h);
                    }
                }
        }
    }
}

// ---------------- MFMA down: grid 4096 (xcd-swizzled), block 512, BN=32 ----------------
__global__ __launch_bounds__(512) void down_kernel(
    const unsigned short* __restrict__ hmid, const float* __restrict__ Wd,
    const int* __restrict__ counts, const int* __restrict__ offsets,
    const int* __restrict__ lists, float* __restrict__ out)
{
    // bijective XCD swizzle: 4096 = 8 * 512
    const int b  = blockIdx.x;
    const int wg = (b & 7) * 512 + (b >> 3);
    const int htile = wg % 64;                // 64 htiles of 32 cols
    const int e     = wg / 64;

    const int count = counts[e];
    if (count == 0) return;
    const int off = offsets[e];
    const int h0 = htile * 32;

    __shared__ unsigned short Alds[BM][40];
    __shared__ u32 Bdl[32 * 20];

    const int tid  = threadIdx.x;
    const int lane = tid & 63;
    const int wid  = tid >> 6;
    const int wm   = wid >> 1, wn = wid & 1;
    const int kb   = lane >> 4;
    const int l15  = lane & 15;

    const float* WdE = Wd + (size_t)e * I_DIM * H_DIM + h0;

    const int ar = tid >> 1;
    const int ah = (tid & 1) * 16;
    const int bnn  = tid & 31;
    const int bkq  = (tid >> 5) & 7;
    const bool bact = tid < 256;
    const int key4w = 4 * ((bnn >> 3) & 3);
    u32* bdst = Bdl + bnn * 20 + ((2 * bkq) ^ key4w);
    const int brn   = wn * 16 + l15;
    const int key4r = 4 * ((brn >> 3) & 3);

    for (int mstart = 0; mstart < count; mstart += BM) {
        const int pr = mstart + ar;
        const bool aact = pr < count;
        const unsigned short* hrow = hmid + (size_t)(off + (aact ? pr : 0)) * I_DIM + ah;
        const bool mact = (mstart + wm * 64) < count;

        f32x4 acc[4];
        #pragma unroll
        for (int i = 0; i < 4; ++i) acc[i] = (f32x4){0.f, 0.f, 0.f, 0.f};

        u32x4 pH0, pH1;
        float d0a, d1a, d2a, d3a;
        float d0b, d1b, d2b, d3b;

#define LOADA(k)                                                                \
        if (aact) {                                                             \
            const u32x4* p_ = (const u32x4*)(hrow + (k));                       \
            pH0 = p_[0]; pH1 = p_[1];                                           \
        }
#define LOADB(R0,R1,R2,R3,k)                                                    \
        if (bact) {                                                             \
            R0 = __builtin_nontemporal_load(WdE + (size_t)((k) + 4 * bkq)     * H_DIM + bnn); \
            R1 = __builtin_nontemporal_load(WdE + (size_t)((k) + 4 * bkq + 1) * H_DIM + bnn); \
            R2 = __builtin_nontemporal_load(WdE + (size_t)((k) + 4 * bkq + 2) * H_DIM + bnn); \
            R3 = __builtin_nontemporal_load(WdE + (size_t)((k) + 4 * bkq + 3) * H_DIM + bnn); \
        }
#define STOREA()                                                                \
        if (aact) {                                                             \
            *(u32x4*)&Alds[ar][ah]     = pH0;                                   \
            *(u32x4*)&Alds[ar][ah + 8] = pH1;                                   \
        }
#define STOREB(R0,R1,R2,R3)                                                     \
        if (bact) {                                                             \
            u32x2 w_; w_.x = pack2(R0, R1); w_.y = pack2(R2, R3);               \
            *(u32x2*)bdst = w_;                                                 \
        }
#define MFMA_PHASE()                                                            \
        if (mact) {                                                             \
            bf16v8 af[4], bd;                                                   \
            _Pragma("unroll")                                                   \
            for (int mf = 0; mf < 4; ++mf)                                      \
                af[mf] = *(const bf16v8*)&Alds[wm * 64 + mf * 16 + l15][kb * 8];\
            bd = *(const bf16v8*)&Bdl[brn * 20 + ((4 * kb) ^ key4r)];           \
            _Pragma("unroll")                                                   \
            for (int mf = 0; mf < 4; ++mf)                                      \
                acc[mf] = __builtin_amdgcn_mfma_f32_16x16x32_bf16(af[mf], bd, acc[mf], 0, 0, 0); \
        }

        LOADB(d0a, d1a, d2a, d3a, 0);
        LOADB(d0b, d1b, d2b, d3b, BKS);
        LOADA(0);

        for (int ii = 0; ii < I_DIM; ii += 2 * BKS) {
            STOREA(); STOREB(d0a, d1a, d2a, d3a);
            __syncthreads();
            if (ii + 2 * BKS < I_DIM) LOADB(d0a, d1a, d2a, d3a, ii + 2 * BKS);
            LOADA(ii + BKS);
            MFMA_PHASE();
            __syncthreads();

            STOREA(); STOREB(d0b, d1b, d2b, d3b);
            __syncthreads();
            if (ii + 3 * BKS < I_DIM) LOADB(d0b, d1b, d2b, d3b, ii + 3 * BKS);
            if (ii + 2 * BKS < I_DIM) LOADA(ii + 2 * BKS);
            MFMA_PHASE();
            __syncthreads();
        }
#undef LOADA
#undef LOADB
#undef STOREA
#undef STOREB
#undef MFMA_PHASE

        if (mact) {
            #pragma unroll
            for (int mf = 0; mf < 4; ++mf)
                #pragma unroll
                for (int r = 0; r < 4; ++r) {
                    int pos = mstart + wm * 64 + mf * 16 + kb * 4 + r;
                    if (pos < count) {
                        int tok = lists[e * NTOK + pos];
                        atomicAdd(&out[(size_t)tok * H_DIM + h0 + wn * 16 + l15],
                                  acc[mf][r]);
                    }
                }
        }
    }
}

extern "C" void kernel_launch(void* const* d_in, const int* in_sizes, int n_in,
                              void* d_out, int out_size, void* d_ws, size_t ws_size,
                              hipStream_t stream) {
    const float* x  = (const float*)d_in[0];
    const float* Wr = (const float*)d_in[1];
    const float* Wg = (const float*)d_in[2];
    const float* Wu = (const float*)d_in[3];
    const float* Wd = (const float*)d_in[4];
    float* out = (float*)d_out;

    char* ws = (char*)d_ws;
    int*   topk_idx = (int*)  (ws + 0);
    float* topk_w   = (float*)(ws + 32768);
    int*   counts   = (int*)  (ws + 65536);
    int*   offsets  = (int*)  (ws + 65792);
    int*   lists    = (int*)  (ws + 66048);
    float* wlist    = (float*)(ws + 328192);
    unsigned short* hmid = (unsigned short*)(ws + 590336);
    unsigned short* xbf  = (unsigned short*)(ws + 13173248);

    const int nout4 = NTOK * H_DIM / 4;
    hipLaunchKernelGGL(zero_kernel, dim3((nout4 + 255) / 256), dim3(256), 0, stream,
                       (float4*)out, nout4);
    hipLaunchKernelGGL(xconv_kernel, dim3((NTOK * H_DIM / 4 + 255) / 256), dim3(256), 0, stream,
                       (const float4*)x, (ushort4*)xbf, NTOK * H_DIM / 4);
    hipLaunchKernelGGL(router_kernel, dim3(NTOK), dim3(64), 0, stream,
                       x, Wr, topk_idx, topk_w);
    hipLaunchKernelGGL(listbuild_kernel, dim3(NEXP), dim3(64), 0, stream,
                       topk_idx, topk_w, counts, lists, wlist);
    hipLaunchKernelGGL(scan_kernel, dim3(1), dim3(64), 0, stream,
                       counts, offsets);
    hipLaunchKernelGGL(gateup_kernel, dim3(24 * NEXP), dim3(512), 0, stream,
                       xbf, Wg, Wu, counts, offsets, lists, wlist, hmid);
    hipLaunchKernelGGL(down_kernel, dim3(64 * NEXP), dim3(512), 0, stream,
                       hmid, Wd, counts, offsets, lists, out);
}